// Round 4
// baseline (291.663 us; speedup 1.0000x reference)
//
#include <hip/hip_runtime.h>
#include <math.h>

#define BB 4
#define NN 4096
#define MP 2048

// v_med3_u32: single-instruction clamp(key, lo, hi) for lo <= hi.
__device__ __forceinline__ unsigned med3u(unsigned a, unsigned b, unsigned c) {
    unsigned d;
    asm("v_med3_u32 %0, %1, %2, %3" : "=v"(d) : "v"(a), "v"(b), "v"(c));
    return d;
}

// Sorted top-16 insert: 15 med3 + 1 min (all static indices -> VGPRs).
#define INSERT16(keys, key)                                    \
    do {                                                       \
        _Pragma("unroll")                                      \
        for (int _k = 15; _k >= 1; --_k)                       \
            keys[_k] = med3u((key), keys[_k - 1], keys[_k]);   \
        keys[0] = min((key), keys[0]);                         \
    } while (0)

#define INSERT16_IF(keys, key)                                 \
    do { if ((key) < keys[15]) INSERT16(keys, key); } while (0)

// ------------------------------------------------------------ fused kernel
// Template over NCH = candidate chunks (CAND = 4096/NCH each).
// Region order (knn FIRST - it is the long pole, so it fills the machine
// while shorter min blocks backfill):
//   knn  [0,   4*16*NCH): pred->pred top-16/chunk, 1 q/thread
//   row  [..,  +4*8*NCH): pred->gt  min, 2 q/thread, per-chunk store
//   col  [..,  +4*8*NCH): gt->pred  min
//   cov  [..,  +4*4*NCH): partial->pred min
template <int NCH>
__global__ __launch_bounds__(256) void kfused(const float* __restrict__ pred,
                                              const float* __restrict__ gt,
                                              const float* __restrict__ partial,
                                              float* __restrict__ wrowc,
                                              float* __restrict__ wcolc,
                                              float* __restrict__ wcovc,
                                              unsigned* __restrict__ wkeys) {
    constexpr int CAND = NN / NCH;
    constexpr int R0 = 4 * 16 * NCH;
    constexpr int R1 = R0 + 4 * 8 * NCH;
    constexpr int R2 = R1 + 4 * 8 * NCH;
    __shared__ float4 cand[CAND];
    int bid = blockIdx.x;

    if (bid < R0) {
        // ---------------- knn path ----------------
        int b = bid / (16 * NCH); int r = bid % (16 * NCH);
        int qb = r / NCH; int ch = r % NCH;
        for (int t = threadIdx.x; t < CAND; t += 256) {
            int j = ch * CAND + t;
            const float* p = pred + ((size_t)b * NN + j) * 3;
            float x = p[0], y = p[1], z = p[2];
            cand[t] = make_float4(x, y, z, fmaf(z, z, fmaf(y, y, x * x)));
        }
        __syncthreads();
        int i = qb * 256 + threadIdx.x;
        const float* q = pred + ((size_t)b * NN + i) * 3;
        float qx = q[0], qy = q[1], qz = q[2];
        float qq = fmaf(qz, qz, fmaf(qy, qy, qx * qx));
        unsigned keys[16];
#pragma unroll
        for (int k = 0; k < 16; ++k) keys[k] = 0xFFFFFFFFu;
        unsigned jbase = (unsigned)(ch * CAND);
        // chain always runs: at chunk<=256 some lane inserts ~every iter,
        // so the branch would be taken anyway; exec-masked ops issue regardless.
#pragma unroll 4
        for (int jj = 0; jj < CAND; ++jj) {
            float4 c = cand[jj];
            float dot = fmaf(qz, c.z, fmaf(qy, c.y, qx * c.x));
            float sq  = fmaxf(fmaf(-2.f, dot, qq + c.w), 0.f);
            unsigned key = (__float_as_uint(sq) & 0xFFFFF000u) | (jbase + (unsigned)jj);
            INSERT16(keys, key);
        }
        size_t base = (((size_t)b * NN + i) * NCH + ch) * 16;
#pragma unroll
        for (int k = 0; k < 16; ++k) wkeys[base + k] = keys[k];
    } else {
        // ---------------- min path ----------------
        const float* qptr; const float* cptr; float* outp;
        int b, qb, ch, qn;
        if (bid < R1) {
            int l = bid - R0;
            b = l / (8 * NCH); int r = l % (8 * NCH); qb = r / NCH; ch = r % NCH;
            qptr = pred; cptr = gt; outp = wrowc; qn = NN;
        } else if (bid < R2) {
            int l = bid - R1;
            b = l / (8 * NCH); int r = l % (8 * NCH); qb = r / NCH; ch = r % NCH;
            qptr = gt; cptr = pred; outp = wcolc; qn = NN;
        } else {
            int l = bid - R2;
            b = l / (4 * NCH); int r = l % (4 * NCH); qb = r / NCH; ch = r % NCH;
            qptr = partial; cptr = pred; outp = wcovc; qn = MP;
        }
        for (int t = threadIdx.x; t < CAND; t += 256) {
            int j = ch * CAND + t;
            const float* p = cptr + ((size_t)b * NN + j) * 3;
            float x = p[0], y = p[1], z = p[2];
            cand[t] = make_float4(x, y, z, fmaf(z, z, fmaf(y, y, x * x)));
        }
        __syncthreads();
        int i0 = qb * 512 + threadIdx.x;
        int i1 = i0 + 256;
        const float* q0 = qptr + ((size_t)b * qn + i0) * 3;
        const float* q1 = qptr + ((size_t)b * qn + i1) * 3;
        float q0x = q0[0], q0y = q0[1], q0z = q0[2];
        float q1x = q1[0], q1y = q1[1], q1z = q1[2];
        float q0q = fmaf(q0z, q0z, fmaf(q0y, q0y, q0x * q0x));
        float q1q = fmaf(q1z, q1z, fmaf(q1y, q1y, q1x * q1x));
        float m0 = 1e30f, m1 = 1e30f;
#pragma unroll 4
        for (int jj = 0; jj < CAND; ++jj) {
            float4 c = cand[jj];
            float d0 = fmaf(q0z, c.z, fmaf(q0y, c.y, q0x * c.x));
            float d1 = fmaf(q1z, c.z, fmaf(q1y, c.y, q1x * c.x));
            m0 = fminf(m0, fmaf(-2.f, d0, q0q + c.w));
            m1 = fminf(m1, fmaf(-2.f, d1, q1q + c.w));
        }
        // per-chunk slot store (no atomics, no init needed)
        outp[(size_t)ch * (4 * qn) + (size_t)b * qn + i0] = fmaxf(m0, 0.f);
        outp[(size_t)ch * (4 * qn) + (size_t)b * qn + i1] = fmaxf(m1, 0.f);
    }
}

// ------------------------------------------------------------ merge stage A
// Per query: merge GS chunk lists (GS*16 keys) -> one list of 16.
// Grid: 64 * G blocks (G = NCH/GS), 256 threads (1 query each).
template <int NCH, int GS>
__global__ __launch_bounds__(256) void kmergeA(const unsigned* __restrict__ wkeys,
                                               unsigned* __restrict__ wkeys2) {
    constexpr int G = NCH / GS;
    int bid = blockIdx.x;
    int qblk = bid / G, g = bid % G;
    int q = qblk * 256 + threadIdx.x;
    unsigned keys[16];
#pragma unroll
    for (int k = 0; k < 16; ++k) keys[k] = 0xFFFFFFFFu;
    const uint4* src = (const uint4*)(wkeys + ((size_t)q * NCH + (size_t)g * GS) * 16);
    for (int c4 = 0; c4 < GS * 4; ++c4) {
        uint4 k4 = src[c4];
        INSERT16_IF(keys, k4.x);
        INSERT16_IF(keys, k4.y);
        INSERT16_IF(keys, k4.z);
        INSERT16_IF(keys, k4.w);
    }
    unsigned* dst = wkeys2 + ((size_t)q * G + g) * 16;
#pragma unroll
    for (int k = 0; k < 16; ++k) dst[k] = keys[k];
}

// ------------------------------------------------------------ merge stage B
// Merge G lists of 16 -> global top-16; gather neighbor coords (L2),
// repulsion (ranks 1..8) + smoothness variance (ranks 0..15).
// 256 blocks x 64 threads, wave-reduced partials (deterministic).
template <int G>
__global__ __launch_bounds__(64) void kmergeB(const float* __restrict__ pred,
                                              const unsigned* __restrict__ wk,
                                              float* __restrict__ partials) {
    int q = blockIdx.x * 64 + threadIdx.x;   // [0, 16384)
    int b = q >> 12;
    int i = q & (NN - 1);
    unsigned keys[16];
#pragma unroll
    for (int k = 0; k < 16; ++k) keys[k] = 0xFFFFFFFFu;
    const uint4* src = (const uint4*)(wk + (size_t)q * (G * 16));
    for (int c4 = 0; c4 < G * 4; ++c4) {
        uint4 k4 = src[c4];
        INSERT16_IF(keys, k4.x);
        INSERT16_IF(keys, k4.y);
        INSERT16_IF(keys, k4.z);
        INSERT16_IF(keys, k4.w);
    }
    const float* qp = pred + ((size_t)b * NN + i) * 3;
    float qx = qp[0], qy = qp[1], qz = qp[2];
    float qq = fmaf(qz, qz, fmaf(qy, qy, qx * qx));
    float cxv[16], cyv[16], czv[16];
#pragma unroll
    for (int r = 0; r < 16; ++r) {
        int idx = (int)(keys[r] & 0xFFFu);
        const float* p = pred + ((size_t)b * NN + idx) * 3;
        cxv[r] = p[0]; cyv[r] = p[1]; czv[r] = p[2];
    }
    float rep = 0.f;
#pragma unroll
    for (int r = 1; r <= 8; ++r) {
        float x = cxv[r], y = cyv[r], z = czv[r];
        float bb2 = fmaf(z, z, fmaf(y, y, x * x));
        float dot = fmaf(qz, z, fmaf(qy, y, qx * x));
        float sq  = fmaxf(fmaf(-2.f, dot, qq + bb2), 0.f);
        float d = (sq > 1e-12f) ? sqrtf(sq) : 0.f;
        rep += fmaxf(0.005f - d, 0.f);
    }
    float sx = 0.f, sy = 0.f, sz = 0.f;
#pragma unroll
    for (int r = 0; r < 16; ++r) { sx += cxv[r]; sy += cyv[r]; sz += czv[r]; }
    float mx = sx * (1.f / 16.f), my = sy * (1.f / 16.f), mz = sz * (1.f / 16.f);
    float var = 0.f;
#pragma unroll
    for (int r = 0; r < 16; ++r) {
        float dx = cxv[r] - mx, dy = cyv[r] - my, dz = czv[r] - mz;
        var += dx * dx + dy * dy + dz * dz;
    }
    var *= (1.f / 47.f);
#pragma unroll
    for (int off = 32; off > 0; off >>= 1) {
        rep += __shfl_down(rep, off);
        var += __shfl_down(var, off);
    }
    if (threadIdx.x == 0) {
        partials[blockIdx.x * 2 + 0] = rep;
        partials[blockIdx.x * 2 + 1] = var;
    }
}

// -------------------------------------------------------------- final kernel
// One block x 1024. Wave-shuffle reductions, a single barrier.
__device__ __forceinline__ float wred(float v) {
#pragma unroll
    for (int off = 32; off > 0; off >>= 1) v += __shfl_down(v, off);
    return v;
}

__global__ __launch_bounds__(1024) void kfinal(const float* __restrict__ wrowc,
                                               const float* __restrict__ wcolc,
                                               const float* __restrict__ wcovc,
                                               const float* __restrict__ partials,
                                               const float* __restrict__ partialpts,
                                               float* __restrict__ out, int nch) {
    __shared__ float lds[16 * 12];
    int t = threadIdx.x;
    float srow = 0.f, scol = 0.f;
    for (int q = t; q < BB * NN; q += 1024) {
        float mr = 1e30f, mc = 1e30f;
        for (int ch = 0; ch < nch; ++ch) {
            mr = fminf(mr, wrowc[(size_t)ch * (BB * NN) + q]);
            mc = fminf(mc, wcolc[(size_t)ch * (BB * NN) + q]);
        }
        srow += (mr > 1e-12f) ? sqrtf(mr) : 0.f;
        scol += (mc > 1e-12f) ? sqrtf(mc) : 0.f;
    }
    float cs0, cs1, cs2, cs3, cc0, cc1, cc2, cc3;
    {
        float s[4], c[4];
#pragma unroll
        for (int b2 = 0; b2 < 4; ++b2) {
            float ss = 0.f, ccv = 0.f;
            for (int qq = t; qq < MP; qq += 1024) {     // static b2 -> VGPRs
                int q = b2 * MP + qq;
                float mv = 1e30f;
                for (int ch = 0; ch < nch; ++ch)
                    mv = fminf(mv, wcovc[(size_t)ch * (BB * MP) + q]);
                const float* p = partialpts + (size_t)q * 3;
                float am = fabsf(p[0]) + fabsf(p[1]) + fabsf(p[2]);
                float m = (am > 1e-6f) ? 1.f : 0.f;
                float d = (mv > 1e-12f) ? sqrtf(mv) : 0.f;
                ss += d * m; ccv += m;
            }
            s[b2] = ss; c[b2] = ccv;
        }
        cs0 = s[0]; cs1 = s[1]; cs2 = s[2]; cs3 = s[3];
        cc0 = c[0]; cc1 = c[1]; cc2 = c[2]; cc3 = c[3];
    }
    float pr = 0.f, pv = 0.f;
    if (t < 256) { pr = partials[t * 2]; pv = partials[t * 2 + 1]; }

    int wid = t >> 6, lane = t & 63;
    float vals0 = srow, vals1 = scol;
#define WSTORE(k, v) { float _r = wred(v); if (lane == 0) lds[wid * 12 + (k)] = _r; }
    WSTORE(0, vals0) WSTORE(1, vals1)
    WSTORE(2, cs0) WSTORE(3, cs1) WSTORE(4, cs2) WSTORE(5, cs3)
    WSTORE(6, cc0) WSTORE(7, cc1) WSTORE(8, cc2) WSTORE(9, cc3)
    WSTORE(10, pr) WSTORE(11, pv)
#undef WSTORE
    __syncthreads();
    if (t == 0) {
        float acc[12];
#pragma unroll
        for (int k = 0; k < 12; ++k) {
            float s = 0.f;
            for (int w = 0; w < 16; ++w) s += lds[w * 12 + k];
            acc[k] = s;
        }
        const float inv_bn = 1.f / (float)(BB * NN);
        float chamfer = (acc[0] + acc[1]) * inv_bn;
        float repulsion = acc[10] * inv_bn * (1.f / 8.f) * 0.1f;
        float per0 = (acc[6] > 0.f) ? acc[2] / fmaxf(acc[6], 1.f) : 0.f;
        float per1 = (acc[7] > 0.f) ? acc[3] / fmaxf(acc[7], 1.f) : 0.f;
        float per2 = (acc[8] > 0.f) ? acc[4] / fmaxf(acc[8], 1.f) : 0.f;
        float per3 = (acc[9] > 0.f) ? acc[5] / fmaxf(acc[9], 1.f) : 0.f;
        float coverage = (per0 + per1 + per2 + per3) * 0.25f * 0.2f;
        float smooth = acc[11] * inv_bn * 0.05f;
        out[0] = chamfer;
        out[1] = repulsion;
        out[2] = coverage;
        out[3] = smooth;
        out[4] = chamfer + repulsion + coverage + smooth;
    }
}

extern "C" void kernel_launch(void* const* d_in, const int* in_sizes, int n_in,
                              void* d_out, int out_size, void* d_ws, size_t ws_size,
                              hipStream_t stream) {
    const float* pred    = (const float*)d_in[0];
    const float* gt      = (const float*)d_in[1];
    const float* partial = (const float*)d_in[2];
    float* out = (float*)d_out;

    const size_t NQ = (size_t)BB * NN;     // 16384
    const size_t NC = (size_t)BB * MP;     // 8192

    // layout: wkeys | wkeys2 | wrowc | wcolc | wcovc | partials  (u32/float)
    auto need = [&](int nch, bool twostage) -> size_t {
        return (NQ * nch * 16 + (twostage ? NQ * 64 : 0) +
                NQ * nch * 2 + NC * nch + 512) * 4;
    };

    unsigned* wkeys = (unsigned*)d_ws;

    if (ws_size >= need(32, true)) {
        constexpr int NCH = 32;
        unsigned* wkeys2 = wkeys + NQ * NCH * 16;
        float* wrowc = (float*)(wkeys2 + NQ * 64);
        float* wcolc = wrowc + NQ * NCH;
        float* wcovc = wcolc + NQ * NCH;
        float* partials = wcovc + NC * NCH;
        kfused<NCH><<<4608, 256, 0, stream>>>(pred, gt, partial, wrowc, wcolc, wcovc, wkeys);
        kmergeA<NCH, 8><<<256, 256, 0, stream>>>(wkeys, wkeys2);
        kmergeB<4><<<256, 64, 0, stream>>>(pred, wkeys2, partials);
        kfinal<<<1, 1024, 0, stream>>>(wrowc, wcolc, wcovc, partials, partial, out, NCH);
    } else if (ws_size >= need(16, true)) {
        constexpr int NCH = 16;
        unsigned* wkeys2 = wkeys + NQ * NCH * 16;
        float* wrowc = (float*)(wkeys2 + NQ * 64);
        float* wcolc = wrowc + NQ * NCH;
        float* wcovc = wcolc + NQ * NCH;
        float* partials = wcovc + NC * NCH;
        kfused<NCH><<<2304, 256, 0, stream>>>(pred, gt, partial, wrowc, wcolc, wcovc, wkeys);
        kmergeA<NCH, 4><<<256, 256, 0, stream>>>(wkeys, wkeys2);
        kmergeB<4><<<256, 64, 0, stream>>>(pred, wkeys2, partials);
        kfinal<<<1, 1024, 0, stream>>>(wrowc, wcolc, wcovc, partials, partial, out, NCH);
    } else {
        constexpr int NCH = 8;
        float* wrowc = (float*)(wkeys + NQ * NCH * 16);
        float* wcolc = wrowc + NQ * NCH;
        float* wcovc = wcolc + NQ * NCH;
        float* partials = wcovc + NC * NCH;
        kfused<NCH><<<1152, 256, 0, stream>>>(pred, gt, partial, wrowc, wcolc, wcovc, wkeys);
        kmergeB<8><<<256, 64, 0, stream>>>(pred, wkeys, partials);
        kfinal<<<1, 1024, 0, stream>>>(wrowc, wcolc, wcovc, partials, partial, out, NCH);
    }
}

// Round 5
// 83.912 us; speedup vs baseline: 3.4758x; 3.4758x over previous
//
#include <hip/hip_runtime.h>
#include <math.h>

#define BB 4
#define NN 4096
#define MP 2048

// v_med3_u32: single-instruction clamp(key, lo, hi) for lo <= hi.
__device__ __forceinline__ unsigned med3u(unsigned a, unsigned b, unsigned c) {
    unsigned d;
    asm("v_med3_u32 %0, %1, %2, %3" : "=v"(d) : "v"(a), "v"(b), "v"(c));
    return d;
}

// Sorted top-16 insert: 15 med3 + 1 min (all static indices -> VGPRs).
#define INSERT16(keys, key)                                    \
    do {                                                       \
        _Pragma("unroll")                                      \
        for (int _k = 15; _k >= 1; --_k)                       \
            keys[_k] = med3u((key), keys[_k - 1], keys[_k]);   \
        keys[0] = min((key), keys[0]);                         \
    } while (0)

#define INSERT16_IF(keys, key)                                 \
    do { if ((key) < keys[15]) INSERT16(keys, key); } while (0)

// ------------------------------------------------------------ fused kernel
// Template over NCH = candidate chunks (CAND = 4096/NCH each).
// Region order (knn FIRST - the long pole fills the machine, min blocks
// backfill):
//   knn  [0,   4*16*NCH): pred->pred top-16/chunk, 1 q/thread
//   row  [..,  +4*8*NCH): pred->gt  min, 2 q/thread, per-chunk store
//   col  [..,  +4*8*NCH): gt->pred  min
//   cov  [..,  +4*4*NCH): partial->pred min
template <int NCH>
__global__ __launch_bounds__(256) void kfused(const float* __restrict__ pred,
                                              const float* __restrict__ gt,
                                              const float* __restrict__ partial,
                                              float* __restrict__ wrowc,
                                              float* __restrict__ wcolc,
                                              float* __restrict__ wcovc,
                                              unsigned* __restrict__ wkeys) {
    constexpr int CAND = NN / NCH;
    constexpr int R0 = 4 * 16 * NCH;
    constexpr int R1 = R0 + 4 * 8 * NCH;
    constexpr int R2 = R1 + 4 * 8 * NCH;
    __shared__ float4 cand[CAND];
    int bid = blockIdx.x;

    if (bid < R0) {
        // ---------------- knn path ----------------
        int b = bid / (16 * NCH); int r = bid % (16 * NCH);
        int qb = r / NCH; int ch = r % NCH;
        for (int t = threadIdx.x; t < CAND; t += 256) {
            int j = ch * CAND + t;
            const float* p = pred + ((size_t)b * NN + j) * 3;
            float x = p[0], y = p[1], z = p[2];
            cand[t] = make_float4(x, y, z, fmaf(z, z, fmaf(y, y, x * x)));
        }
        __syncthreads();
        int i = qb * 256 + threadIdx.x;
        const float* q = pred + ((size_t)b * NN + i) * 3;
        float qx = q[0], qy = q[1], qz = q[2];
        float qq = fmaf(qz, qz, fmaf(qy, qy, qx * qx));
        unsigned keys[16];
#pragma unroll
        for (int k = 0; k < 16; ++k) keys[k] = 0xFFFFFFFFu;
        unsigned jbase = (unsigned)(ch * CAND);
#pragma unroll 4
        for (int jj = 0; jj < CAND; ++jj) {
            float4 c = cand[jj];
            float dot = fmaf(qz, c.z, fmaf(qy, c.y, qx * c.x));
            float sq  = fmaxf(fmaf(-2.f, dot, qq + c.w), 0.f);
            unsigned key = (__float_as_uint(sq) & 0xFFFFF000u) | (jbase + (unsigned)jj);
            INSERT16(keys, key);
        }
        size_t base = (((size_t)b * NN + i) * NCH + ch) * 16;
        uint4* dst = (uint4*)(wkeys + base);
        dst[0] = make_uint4(keys[0], keys[1], keys[2], keys[3]);
        dst[1] = make_uint4(keys[4], keys[5], keys[6], keys[7]);
        dst[2] = make_uint4(keys[8], keys[9], keys[10], keys[11]);
        dst[3] = make_uint4(keys[12], keys[13], keys[14], keys[15]);
    } else {
        // ---------------- min path ----------------
        const float* qptr; const float* cptr; float* outp;
        int b, qb, ch, qn;
        if (bid < R1) {
            int l = bid - R0;
            b = l / (8 * NCH); int r = l % (8 * NCH); qb = r / NCH; ch = r % NCH;
            qptr = pred; cptr = gt; outp = wrowc; qn = NN;
        } else if (bid < R2) {
            int l = bid - R1;
            b = l / (8 * NCH); int r = l % (8 * NCH); qb = r / NCH; ch = r % NCH;
            qptr = gt; cptr = pred; outp = wcolc; qn = NN;
        } else {
            int l = bid - R2;
            b = l / (4 * NCH); int r = l % (4 * NCH); qb = r / NCH; ch = r % NCH;
            qptr = partial; cptr = pred; outp = wcovc; qn = MP;
        }
        for (int t = threadIdx.x; t < CAND; t += 256) {
            int j = ch * CAND + t;
            const float* p = cptr + ((size_t)b * NN + j) * 3;
            float x = p[0], y = p[1], z = p[2];
            cand[t] = make_float4(x, y, z, fmaf(z, z, fmaf(y, y, x * x)));
        }
        __syncthreads();
        int i0 = qb * 512 + threadIdx.x;
        int i1 = i0 + 256;
        const float* q0 = qptr + ((size_t)b * qn + i0) * 3;
        const float* q1 = qptr + ((size_t)b * qn + i1) * 3;
        float q0x = q0[0], q0y = q0[1], q0z = q0[2];
        float q1x = q1[0], q1y = q1[1], q1z = q1[2];
        float q0q = fmaf(q0z, q0z, fmaf(q0y, q0y, q0x * q0x));
        float q1q = fmaf(q1z, q1z, fmaf(q1y, q1y, q1x * q1x));
        float m0 = 1e30f, m1 = 1e30f;
#pragma unroll 4
        for (int jj = 0; jj < CAND; ++jj) {
            float4 c = cand[jj];
            float d0 = fmaf(q0z, c.z, fmaf(q0y, c.y, q0x * c.x));
            float d1 = fmaf(q1z, c.z, fmaf(q1y, c.y, q1x * c.x));
            m0 = fminf(m0, fmaf(-2.f, d0, q0q + c.w));
            m1 = fminf(m1, fmaf(-2.f, d1, q1q + c.w));
        }
        outp[(size_t)ch * (4 * qn) + (size_t)b * qn + i0] = fmaxf(m0, 0.f);
        outp[(size_t)ch * (4 * qn) + (size_t)b * qn + i1] = fmaxf(m1, 0.f);
    }
}

// ------------------------------------------------------------ mid kernel
// Region 1 [0, 64*G):   mergeA - per query merge GS chunk lists -> 1 of 16.
// Region 2 [.., +160):  kred   - parallel chunk-min reduction + sqrt + mask,
//                                block-reduced to partials2[160] pairs.
// Both depend only on kfused -> single dispatch.
template <int NCH, int GS>
__global__ __launch_bounds__(256) void kmid(const unsigned* __restrict__ wkeys,
                                            unsigned* __restrict__ wkeys2,
                                            const float* __restrict__ wrowc,
                                            const float* __restrict__ wcolc,
                                            const float* __restrict__ wcovc,
                                            const float* __restrict__ partialpts,
                                            float2* __restrict__ partials2) {
    constexpr int G = (GS > 0) ? NCH / GS : 0;
    constexpr int RM = 64 * G;
    int bid = blockIdx.x;
    int t = threadIdx.x;

    if (GS > 0 && bid < RM) {
        // ---------------- mergeA ----------------
        int qblk = bid / G, g = bid % G;
        int q = qblk * 256 + t;
        unsigned keys[16];
#pragma unroll
        for (int k = 0; k < 16; ++k) keys[k] = 0xFFFFFFFFu;
        const uint4* src = (const uint4*)(wkeys + ((size_t)q * NCH + (size_t)g * GS) * 16);
        for (int c4 = 0; c4 < GS * 4; ++c4) {
            uint4 k4 = src[c4];
            INSERT16_IF(keys, k4.x);
            INSERT16_IF(keys, k4.y);
            INSERT16_IF(keys, k4.z);
            INSERT16_IF(keys, k4.w);
        }
        uint4* dst = (uint4*)(wkeys2 + ((size_t)q * G + g) * 16);
        dst[0] = make_uint4(keys[0], keys[1], keys[2], keys[3]);
        dst[1] = make_uint4(keys[4], keys[5], keys[6], keys[7]);
        dst[2] = make_uint4(keys[8], keys[9], keys[10], keys[11]);
        dst[3] = make_uint4(keys[12], keys[13], keys[14], keys[15]);
    } else {
        // ---------------- kred ----------------
        __shared__ float ra[4], rb[4];
        int bid2 = bid - RM;
        float pa = 0.f, pb = 0.f;
        if (bid2 < 64) {                       // row mins
            int q = bid2 * 256 + t;
            float m = 1e30f;
#pragma unroll
            for (int ch = 0; ch < NCH; ++ch)
                m = fminf(m, wrowc[(size_t)ch * (BB * NN) + q]);
            pa = (m > 1e-12f) ? sqrtf(m) : 0.f;
        } else if (bid2 < 128) {               // col mins
            int q = (bid2 - 64) * 256 + t;
            float m = 1e30f;
#pragma unroll
            for (int ch = 0; ch < NCH; ++ch)
                m = fminf(m, wcolc[(size_t)ch * (BB * NN) + q]);
            pa = (m > 1e-12f) ? sqrtf(m) : 0.f;
        } else {                               // cov mins + mask
            int q = (bid2 - 128) * 256 + t;    // [0, 8192), block within one batch
            float m = 1e30f;
#pragma unroll
            for (int ch = 0; ch < NCH; ++ch)
                m = fminf(m, wcovc[(size_t)ch * (BB * MP) + q]);
            const float* p = partialpts + (size_t)q * 3;
            float am = fabsf(p[0]) + fabsf(p[1]) + fabsf(p[2]);
            float msk = (am > 1e-6f) ? 1.f : 0.f;
            float d = (m > 1e-12f) ? sqrtf(m) : 0.f;
            pa = d * msk; pb = msk;
        }
        // block reduce 256 -> 1 (wave shuffles + 4-slot LDS)
#pragma unroll
        for (int off = 32; off > 0; off >>= 1) {
            pa += __shfl_down(pa, off);
            pb += __shfl_down(pb, off);
        }
        int wid = t >> 6, lane = t & 63;
        if (lane == 0) { ra[wid] = pa; rb[wid] = pb; }
        __syncthreads();
        if (t == 0)
            partials2[bid2] = make_float2(ra[0] + ra[1] + ra[2] + ra[3],
                                          rb[0] + rb[1] + rb[2] + rb[3]);
    }
}

// ------------------------------------------------------------ merge stage B
// Merge G lists of 16 -> global top-16; gather neighbor coords (L2),
// repulsion (ranks 1..8) + smoothness variance (ranks 0..15).
// 256 blocks x 64 threads, wave-reduced partials (deterministic).
template <int G>
__global__ __launch_bounds__(64) void kmergeB(const float* __restrict__ pred,
                                              const unsigned* __restrict__ wk,
                                              float2* __restrict__ partialsB) {
    int q = blockIdx.x * 64 + threadIdx.x;   // [0, 16384)
    int b = q >> 12;
    int i = q & (NN - 1);
    unsigned keys[16];
#pragma unroll
    for (int k = 0; k < 16; ++k) keys[k] = 0xFFFFFFFFu;
    const uint4* src = (const uint4*)(wk + (size_t)q * (G * 16));
    for (int c4 = 0; c4 < G * 4; ++c4) {
        uint4 k4 = src[c4];
        INSERT16_IF(keys, k4.x);
        INSERT16_IF(keys, k4.y);
        INSERT16_IF(keys, k4.z);
        INSERT16_IF(keys, k4.w);
    }
    const float* qp = pred + ((size_t)b * NN + i) * 3;
    float qx = qp[0], qy = qp[1], qz = qp[2];
    float qq = fmaf(qz, qz, fmaf(qy, qy, qx * qx));
    float cxv[16], cyv[16], czv[16];
#pragma unroll
    for (int r = 0; r < 16; ++r) {
        int idx = (int)(keys[r] & 0xFFFu);
        const float* p = pred + ((size_t)b * NN + idx) * 3;
        cxv[r] = p[0]; cyv[r] = p[1]; czv[r] = p[2];
    }
    float rep = 0.f;
#pragma unroll
    for (int r = 1; r <= 8; ++r) {
        float x = cxv[r], y = cyv[r], z = czv[r];
        float bb2 = fmaf(z, z, fmaf(y, y, x * x));
        float dot = fmaf(qz, z, fmaf(qy, y, qx * x));
        float sq  = fmaxf(fmaf(-2.f, dot, qq + bb2), 0.f);
        float d = (sq > 1e-12f) ? sqrtf(sq) : 0.f;
        rep += fmaxf(0.005f - d, 0.f);
    }
    float sx = 0.f, sy = 0.f, sz = 0.f;
#pragma unroll
    for (int r = 0; r < 16; ++r) { sx += cxv[r]; sy += cyv[r]; sz += czv[r]; }
    float mx = sx * (1.f / 16.f), my = sy * (1.f / 16.f), mz = sz * (1.f / 16.f);
    float var = 0.f;
#pragma unroll
    for (int r = 0; r < 16; ++r) {
        float dx = cxv[r] - mx, dy = cyv[r] - my, dz = czv[r] - mz;
        var += dx * dx + dy * dy + dz * dz;
    }
    var *= (1.f / 47.f);
#pragma unroll
    for (int off = 32; off > 0; off >>= 1) {
        rep += __shfl_down(rep, off);
        var += __shfl_down(var, off);
    }
    if (threadIdx.x == 0) partialsB[blockIdx.x] = make_float2(rep, var);
}

// -------------------------------------------------------------- final kernel
// 1 block x 256 (4 waves), one barrier. Combines 160 + 256 partial pairs.
__global__ __launch_bounds__(256) void kfinal2(const float2* __restrict__ partials2,
                                               const float2* __restrict__ partialsB,
                                               float* __restrict__ out) {
    __shared__ float lds[12];
    int t = threadIdx.x;
    int wid = t >> 6, lane = t & 63;
    if (wid == 0) {                      // srow over partials2[0..64)
        float v = partials2[lane].x;
#pragma unroll
        for (int off = 32; off > 0; off >>= 1) v += __shfl_down(v, off);
        if (lane == 0) lds[0] = v;
    } else if (wid == 1) {               // scol over partials2[64..128)
        float v = partials2[64 + lane].x;
#pragma unroll
        for (int off = 32; off > 0; off >>= 1) v += __shfl_down(v, off);
        if (lane == 0) lds[1] = v;
    } else if (wid == 2) {               // cov per batch over partials2[128..160)
        float ss = 0.f, cc = 0.f;
        if (lane < 32) { float2 p = partials2[128 + lane]; ss = p.x; cc = p.y; }
#pragma unroll
        for (int off = 4; off > 0; off >>= 1) {   // reduce within 8-lane groups
            ss += __shfl_down(ss, off, 8);
            cc += __shfl_down(cc, off, 8);
        }
        if (lane < 32 && (lane & 7) == 0) {
            int bb = lane >> 3;
            lds[4 + 2 * bb] = ss;
            lds[5 + 2 * bb] = cc;
        }
    } else {                             // rep/var over partialsB[0..256)
        float2 p0 = partialsB[lane];
        float2 p1 = partialsB[64 + lane];
        float2 p2 = partialsB[128 + lane];
        float2 p3 = partialsB[192 + lane];
        float rep = p0.x + p1.x + p2.x + p3.x;
        float var = p0.y + p1.y + p2.y + p3.y;
#pragma unroll
        for (int off = 32; off > 0; off >>= 1) {
            rep += __shfl_down(rep, off);
            var += __shfl_down(var, off);
        }
        if (lane == 0) { lds[2] = rep; lds[3] = var; }
    }
    __syncthreads();
    if (t == 0) {
        const float inv_bn = 1.f / (float)(BB * NN);
        float chamfer = (lds[0] + lds[1]) * inv_bn;
        float repulsion = lds[2] * inv_bn * (1.f / 8.f) * 0.1f;
        float cov = 0.f;
#pragma unroll
        for (int bb = 0; bb < 4; ++bb) {
            float cs = lds[4 + 2 * bb], cc = lds[5 + 2 * bb];
            cov += (cc > 0.f) ? cs / fmaxf(cc, 1.f) : 0.f;
        }
        float coverage = cov * 0.25f * 0.2f;
        float smooth = lds[3] * inv_bn * 0.05f;
        out[0] = chamfer;
        out[1] = repulsion;
        out[2] = coverage;
        out[3] = smooth;
        out[4] = chamfer + repulsion + coverage + smooth;
    }
}

extern "C" void kernel_launch(void* const* d_in, const int* in_sizes, int n_in,
                              void* d_out, int out_size, void* d_ws, size_t ws_size,
                              hipStream_t stream) {
    const float* pred    = (const float*)d_in[0];
    const float* gt      = (const float*)d_in[1];
    const float* partial = (const float*)d_in[2];
    float* out = (float*)d_out;

    const size_t NQ = (size_t)BB * NN;     // 16384
    const size_t NC = (size_t)BB * MP;     // 8192

    // layout (u32 units): wkeys | wkeys2 | wrowc | wcolc | wcovc | pB | p2
    auto need = [&](int nch, bool twostage) -> size_t {
        return (NQ * nch * 16 + (twostage ? NQ * 64 : 0) +
                NQ * nch * 2 + NC * nch + 512 + 320 + 64) * 4;
    };

    unsigned* wkeys = (unsigned*)d_ws;

    if (ws_size >= need(32, true)) {
        constexpr int NCH = 32;
        unsigned* wkeys2 = wkeys + NQ * NCH * 16;
        float* wrowc = (float*)(wkeys2 + NQ * 64);
        float* wcolc = wrowc + NQ * NCH;
        float* wcovc = wcolc + NQ * NCH;
        float2* pB = (float2*)(wcovc + NC * NCH);
        float2* p2 = pB + 256;
        kfused<NCH><<<4608, 256, 0, stream>>>(pred, gt, partial, wrowc, wcolc, wcovc, wkeys);
        kmid<NCH, 8><<<416, 256, 0, stream>>>(wkeys, wkeys2, wrowc, wcolc, wcovc, partial, p2);
        kmergeB<4><<<256, 64, 0, stream>>>(pred, wkeys2, pB);
        kfinal2<<<1, 256, 0, stream>>>(p2, pB, out);
    } else if (ws_size >= need(16, true)) {
        constexpr int NCH = 16;
        unsigned* wkeys2 = wkeys + NQ * NCH * 16;
        float* wrowc = (float*)(wkeys2 + NQ * 64);
        float* wcolc = wrowc + NQ * NCH;
        float* wcovc = wcolc + NQ * NCH;
        float2* pB = (float2*)(wcovc + NC * NCH);
        float2* p2 = pB + 256;
        kfused<NCH><<<2304, 256, 0, stream>>>(pred, gt, partial, wrowc, wcolc, wcovc, wkeys);
        kmid<NCH, 4><<<416, 256, 0, stream>>>(wkeys, wkeys2, wrowc, wcolc, wcovc, partial, p2);
        kmergeB<4><<<256, 64, 0, stream>>>(pred, wkeys2, pB);
        kfinal2<<<1, 256, 0, stream>>>(p2, pB, out);
    } else {
        constexpr int NCH = 8;
        float* wrowc = (float*)(wkeys + NQ * NCH * 16);
        float* wcolc = wrowc + NQ * NCH;
        float* wcovc = wcolc + NQ * NCH;
        float2* pB = (float2*)(wcovc + NC * NCH);
        float2* p2 = pB + 256;
        kfused<NCH><<<1152, 256, 0, stream>>>(pred, gt, partial, wrowc, wcolc, wcovc, wkeys);
        kmid<NCH, 0><<<160, 256, 0, stream>>>(wkeys, nullptr, wrowc, wcolc, wcovc, partial, p2);
        kmergeB<8><<<256, 64, 0, stream>>>(pred, wkeys, pB);
        kfinal2<<<1, 256, 0, stream>>>(p2, pB, out);
    }
}